// Round 17
// baseline (331.498 us; speedup 1.0000x reference)
//
#include <hip/hip_runtime.h>
#include <hip/hip_fp16.h>

// ---------------------------------------------------------------------------
// GNNEncoder: 4x SAGEConv + linear. R16 = R15 + L2-resident split gathers:
//  - t stored as TWO half-tables tL/tH (N x 32 fp16 = 3.2MB each < 4MB
//    per-XCD L2). Each 64-dim gather -> 2 sequential gather_half passes whose
//    hot table fully fits L2 (R13 evidence: gather FETCH=56MB L2-fill for a
//    6.4MB table = thrash). adj/u are single-use streams -> NT LOADS (keeps
//    L2 for t; R6's NT mistake was stores of consumer-bound data).
//  - final composed layer (Wlin folded into 2b, R15) is already 32-wide ->
//    same gather_half kernel, no relu.
//  - CSR: bucket_scatter_direct + csr_fill2 (38K global atomics, R10 lesson:
//    each global atomic costs ~32B memory-side write).
//  - mm_dual K-chunk 32 (25.6KB LDS, 6 blk/CU), writes tL/tH by col half.
// ---------------------------------------------------------------------------

#define CHUNK 4096          // edges per scatter block
#define EPT 16              // edges per thread (CHUNK/256)
#define SLICE_W 512         // nodes per slice (dst>>9)
#define MAXS 128            // max slices (N <= 65536)

typedef float v4f __attribute__((ext_vector_type(4)));

// ---- one-pass bucket scatter: LDS rank + per-(block,slice) range claim ----
__global__ __launch_bounds__(256) void bucket_scatter_direct(
    const int* __restrict__ e32, int* __restrict__ scnt,
    unsigned* __restrict__ bedge, int E, int S, int bcap)
{
    __shared__ int h[MAXS];    // per-slice count in this block
    __shared__ int hb[MAXS];   // claimed global base
    const int tid = threadIdx.x, b = blockIdx.x;
    for (int i = tid; i < S; i += 256) h[i] = 0;
    __syncthreads();
    const int lo = b * CHUNK;
    unsigned v[EPT];
    int sl[EPT], rk[EPT];
    #pragma unroll
    for (int k = 0; k < EPT; ++k) {
        const int e = lo + k * 256 + tid;
        sl[k] = -1;
        if (e < E) {
            const int s = e32[e], d = e32[E + e];
            v[k]  = ((unsigned)s << 16) | (unsigned)d;
            sl[k] = d >> 9;
            rk[k] = atomicAdd(&h[sl[k]], 1);      // LDS rank
        }
    }
    __syncthreads();
    for (int i = tid; i < S; i += 256)
        hb[i] = h[i] ? atomicAdd(&scnt[i], h[i]) : 0;   // one claim/slice
    __syncthreads();
    #pragma unroll
    for (int k = 0; k < EPT; ++k) {
        if (sl[k] >= 0) {
            const int pos = hb[sl[k]] + rk[k];
            if (pos < bcap)    // statistical impossibility; guards OOB
                bedge[(size_t)sl[k] * bcap + pos] = v[k];
        }
    }
}

// ---- per-slice CSR finalize: rbeg, deg, inv, adj (LDS count+scan+cursor) ----
__global__ __launch_bounds__(1024) void csr_fill2(
    const unsigned* __restrict__ bedge, const int* __restrict__ scnt,
    int* __restrict__ rbeg, int* __restrict__ deg,
    float* __restrict__ inv, unsigned short* __restrict__ adj,
    int N, int bcap)
{
    __shared__ int cnt[SLICE_W];
    __shared__ int sc[SLICE_W];
    const int s = blockIdx.x, tid = threadIdx.x;
    const int n = min(scnt[s], bcap);
    const size_t base = (size_t)s * bcap;
    if (tid < SLICE_W) cnt[tid] = 0;
    __syncthreads();
    for (int i = tid; i < n; i += 1024)
        atomicAdd(&cnt[bedge[base + i] & (SLICE_W - 1)], 1);
    __syncthreads();
    if (tid < SLICE_W) sc[tid] = cnt[tid];
    __syncthreads();
    for (int off = 1; off < SLICE_W; off <<= 1) {
        int a = 0;
        if (tid < SLICE_W && tid >= off) a = sc[tid - off];
        __syncthreads();
        if (tid < SLICE_W) sc[tid] += a;
        __syncthreads();
    }
    if (tid < SLICE_W) {
        const int c = cnt[tid];
        const int excl = sc[tid] - c;
        const int node = (s << 9) + tid;
        if (node < N) {
            rbeg[node] = (int)base + excl;
            deg[node]  = c;
            inv[node]  = 1.0f / (float)(c > 0 ? c : 1);
        }
        cnt[tid] = excl;                   // becomes the cursor
    }
    __syncthreads();
    for (int i = tid; i < n; i += 1024) {
        const unsigned v = bedge[base + i];
        const int p = atomicAdd(&cnt[v & (SLICE_W - 1)], 1);   // LDS cursor
        adj[base + p] = (unsigned short)(v >> 16);
    }
}

// ---- compose: C1 = W2b_l@Wlin, C2 = W2b_r@Wlin, cb = b2b@Wlin + blin ----
__global__ __launch_bounds__(256) void compose(
    const float* __restrict__ Wl, const float* __restrict__ Wr,
    const float* __restrict__ b2, const float* __restrict__ Wlin,
    const float* __restrict__ blin, float* __restrict__ C1,
    float* __restrict__ C2, float* __restrict__ cb)
{
    __shared__ float Ws[64 * 32];
    const int tid = threadIdx.x;
    for (int i = tid * 4; i < 64 * 32; i += 1024)
        *(float4*)&Ws[i] = *(const float4*)&Wlin[i];
    __syncthreads();
    for (int idx = tid; idx < 64 * 32; idx += 256) {
        const int r = idx >> 5, c = idx & 31;
        float s1 = 0.f, s2 = 0.f;
        #pragma unroll 8
        for (int k = 0; k < 64; ++k) {
            const float w = Ws[k * 32 + c];
            s1 += Wl[r * 64 + k] * w;
            s2 += Wr[r * 64 + k] * w;
        }
        C1[idx] = s1;
        C2[idx] = s2;
    }
    if (tid < 32) {
        float s = blin[tid];
        #pragma unroll 8
        for (int k = 0; k < 64; ++k) s += b2[k] * Ws[k * 32 + tid];
        cb[tid] = s;
    }
}

// 32-dim pull aggregation over a HALF table (N x 32 fp16, 3.2MB -> L2-fits):
// out[node, d] = (relu)(u[node,d] + inv * sum_j t[adj_j, d]), d in my half.
// one wave per node: 16 neighbor-groups x 4 dim-lanes, half8 (16B) per lane.
// u/out are pre-offset to the half; row stride = STRIDE. adj/u NT-loaded.
template<bool RELU, int STRIDE>
__global__ __launch_bounds__(256) void gather_half(
    const __half* __restrict__ t, const unsigned short* __restrict__ adj,
    const int* __restrict__ rbeg, const int* __restrict__ deg,
    const float* __restrict__ inv, const __half* __restrict__ u,
    float* __restrict__ out, int N)
{
    const int node = (blockIdx.x * 256 + threadIdx.x) >> 6;
    const int lane = threadIdx.x & 63;
    const int grp  = lane >> 2;          // 0..15: neighbor slot
    const int d0   = (lane & 3) * 8;     // dim offset (8 dims per lane)
    if (node >= N) return;
    const int beg = rbeg[node];
    const int end = beg + deg[node];
    float a[8] = {0.f, 0.f, 0.f, 0.f, 0.f, 0.f, 0.f, 0.f};
    int j = beg + grp;
    for (; j + 16 < end; j += 32) {      // 2x unrolled: j and j+16
        const int n0 = __builtin_nontemporal_load(adj + j);
        const int n1 = __builtin_nontemporal_load(adj + j + 16);
        const float4 p0 = *(const float4*)(t + (size_t)n0 * 32 + d0);
        const float4 p1 = *(const float4*)(t + (size_t)n1 * 32 + d0);
        const __half2* h0 = (const __half2*)&p0;
        const __half2* h1 = (const __half2*)&p1;
        #pragma unroll
        for (int k = 0; k < 4; ++k) {
            float2 f0 = __half22float2(h0[k]);
            float2 f1 = __half22float2(h1[k]);
            a[2 * k]     += f0.x + f1.x;
            a[2 * k + 1] += f0.y + f1.y;
        }
    }
    if (j < end) {
        const int nl = __builtin_nontemporal_load(adj + j);
        const float4 p0 = *(const float4*)(t + (size_t)nl * 32 + d0);
        const __half2* h0 = (const __half2*)&p0;
        #pragma unroll
        for (int k = 0; k < 4; ++k) {
            float2 f0 = __half22float2(h0[k]);
            a[2 * k]     += f0.x;
            a[2 * k + 1] += f0.y;
        }
    }
    // reduce across the 16 groups (lane bits 2,3,4,5)
    #pragma unroll
    for (int k = 0; k < 8; ++k) {
        a[k] += __shfl_xor(a[k], 4);
        a[k] += __shfl_xor(a[k], 8);
        a[k] += __shfl_xor(a[k], 16);
        a[k] += __shfl_xor(a[k], 32);
    }
    if (grp == 0) {
        const float vi = inv[node];
        union { v4f v; __half2 h[4]; } uu;
        uu.v = __builtin_nontemporal_load(
            (const v4f*)(u + (size_t)node * STRIDE + d0));
        float4 o0, o1;
        float2 g0 = __half22float2(uu.h[0]);
        float2 g1 = __half22float2(uu.h[1]);
        float2 g2 = __half22float2(uu.h[2]);
        float2 g3 = __half22float2(uu.h[3]);
        o0.x = g0.x + a[0] * vi; o0.y = g0.y + a[1] * vi;
        o0.z = g1.x + a[2] * vi; o0.w = g1.y + a[3] * vi;
        o1.x = g2.x + a[4] * vi; o1.y = g2.y + a[5] * vi;
        o1.z = g3.x + a[6] * vi; o1.w = g3.y + a[7] * vi;
        if (RELU) {
            o0.x = fmaxf(o0.x, 0.f); o0.y = fmaxf(o0.y, 0.f);
            o0.z = fmaxf(o0.z, 0.f); o0.w = fmaxf(o0.w, 0.f);
            o1.x = fmaxf(o1.x, 0.f); o1.y = fmaxf(o1.y, 0.f);
            o1.z = fmaxf(o1.z, 0.f); o1.w = fmaxf(o1.w, 0.f);
        }
        *(float4*)(out + (size_t)node * STRIDE + d0)     = o0;
        *(float4*)(out + (size_t)node * STRIDE + d0 + 4) = o1;
    }
}

// T(fp16, split tL/tH by col half for DOUT=64; single tL for DOUT=32)
//   = A[M,K]@Wl ; U[M,DOUT](fp16) = A[M,K]@Wr + b.  K-chunk 32.
template<int K, int DOUT>
__global__ __launch_bounds__(256) void mm_dual(
    const float* __restrict__ A, const float* __restrict__ Wl,
    const float* __restrict__ Wr, const float* __restrict__ bias,
    __half* __restrict__ TL, __half* __restrict__ TH,
    __half* __restrict__ U, int M)
{
    constexpr int CT = DOUT / 16;
    __shared__ float As[64][36];
    __shared__ float Wls[32 * DOUT];
    __shared__ float Wrs[32 * DOUT];
    const int tid  = threadIdx.x;
    const int row0 = blockIdx.x * 64;
    const int tx = tid & 15, ty = tid >> 4;
    float accT[4][CT], accU[4][CT];
    #pragma unroll
    for (int r = 0; r < 4; ++r)
        #pragma unroll
        for (int c = 0; c < CT; ++c) { accT[r][c] = 0.f; accU[r][c] = 0.f; }

    for (int kc = 0; kc < K; kc += 32) {
        if (kc) __syncthreads();
        for (int i = tid * 4; i < 64 * 32; i += 1024) {
            int r = i >> 5, c = i & 31;
            int gr = row0 + r;
            float4 v = make_float4(0.f, 0.f, 0.f, 0.f);
            if (gr < M) v = *(const float4*)&A[(size_t)gr * K + kc + c];
            *(float4*)&As[r][c] = v;
        }
        for (int i = tid * 4; i < 32 * DOUT; i += 1024) {
            *(float4*)&Wls[i] = *(const float4*)&Wl[kc * DOUT + i];
            *(float4*)&Wrs[i] = *(const float4*)&Wr[kc * DOUT + i];
        }
        __syncthreads();
        #pragma unroll 4
        for (int kk = 0; kk < 32; ++kk) {
            float a[4];
            #pragma unroll
            for (int r = 0; r < 4; ++r) a[r] = As[ty * 4 + r][kk];
            float bl[CT], br[CT];
            #pragma unroll
            for (int c = 0; c < CT; ++c) {
                bl[c] = Wls[kk * DOUT + tx * CT + c];
                br[c] = Wrs[kk * DOUT + tx * CT + c];
            }
            #pragma unroll
            for (int r = 0; r < 4; ++r)
                #pragma unroll
                for (int c = 0; c < CT; ++c) {
                    accT[r][c] += a[r] * bl[c];
                    accU[r][c] += a[r] * br[c];
                }
        }
    }

    float bv[CT];
    #pragma unroll
    for (int c = 0; c < CT; ++c) bv[c] = bias[tx * CT + c];
    #pragma unroll
    for (int r = 0; r < 4; ++r) {
        int gr = row0 + ty * 4 + r;
        if (gr >= M) continue;
        if (CT == 4) {
            // T split: cols [0,32) -> TL, [32,64) -> TH (both N x 32)
            __half* Td = (tx < 8) ? TL : TH;
            const int tcol = (tx * 4) & 31;
            union { int2 v; __half2 h[2]; } tp;
            tp.h[0] = __floats2half2_rn(accT[r][0], accT[r][1]);
            tp.h[1] = __floats2half2_rn(accT[r][2], accT[r][3]);
            *(int2*)&Td[(size_t)gr * 32 + tcol] = tp.v;
            union { int2 v; __half2 h[2]; } up;
            up.h[0] = __floats2half2_rn(accU[r][0] + bv[0], accU[r][1] + bv[1]);
            up.h[1] = __floats2half2_rn(accU[r][2] + bv[2], accU[r][3] + bv[3]);
            *(int2*)&U[(size_t)gr * DOUT + tx * 4] = up.v;
        } else {
            union { int v; __half2 h; } tp;
            tp.h = __floats2half2_rn(accT[r][0], accT[r][1]);
            *(int*)&TL[(size_t)gr * 32 + tx * 2] = tp.v;
            union { int v; __half2 h; } up;
            up.h = __floats2half2_rn(accU[r][0] + bv[0], accU[r][1] + bv[1]);
            *(int*)&U[(size_t)gr * DOUT + tx * 2] = up.v;
        }
    }
}

extern "C" void kernel_launch(void* const* d_in, const int* in_sizes, int n_in,
                              void* d_out, int out_size, void* d_ws, size_t ws_size,
                              hipStream_t stream) {
    const float* x     = (const float*)d_in[0];
    const int*   ei    = (const int*)  d_in[1];
    const float* W1a_l = (const float*)d_in[2];
    const float* b1a   = (const float*)d_in[3];
    const float* W1a_r = (const float*)d_in[4];
    const float* W1b_l = (const float*)d_in[5];
    const float* b1b   = (const float*)d_in[6];
    const float* W1b_r = (const float*)d_in[7];
    const float* W2a_l = (const float*)d_in[8];
    const float* b2a   = (const float*)d_in[9];
    const float* W2a_r = (const float*)d_in[10];
    const float* W2b_l = (const float*)d_in[11];
    const float* b2b   = (const float*)d_in[12];
    const float* W2b_r = (const float*)d_in[13];
    const float* Wlin  = (const float*)d_in[14];
    const float* blin  = (const float*)d_in[15];

    const int N = in_sizes[0] / 128;
    const int E = in_sizes[1] / 2;
    const int S = (N + SLICE_W - 1) / SLICE_W;       // 98 slices @ N=50k
    const int B = (E + CHUNK - 1) / CHUNK;           // 391 blocks @ E=1.6M
    const int bcap = (((E + S - 1) / S) + 2048 + 15) & ~15;  // slice capacity

    size_t o = 0;
    auto take = [&](size_t bytes) -> void* {
        void* p = (char*)d_ws + o;
        o += (bytes + 255) & ~(size_t)255;
        return p;
    };
    int*            scnt  = (int*)     take((size_t)S * 4);
    unsigned*       bedge = (unsigned*)take((size_t)S * bcap * 4);
    int*            rbeg  = (int*)     take((size_t)N * 4);
    int*            deg   = (int*)     take((size_t)N * 4);
    float*          inv   = (float*)   take((size_t)N * 4);
    unsigned short* adj   = (unsigned short*)take((size_t)S * bcap * 2);
    __half*         tL    = (__half*)  take((size_t)N * 32 * 2);
    __half*         tH    = (__half*)  take((size_t)N * 32 * 2);
    __half*         u     = (__half*)  take((size_t)N * 64 * 2);
    float*          hA    = (float*)   take((size_t)N * 64 * 4);
    float*          hB    = (float*)   take((size_t)N * 64 * 4);
    float*          C1    = (float*)   take((size_t)64 * 32 * 4);
    float*          C2    = (float*)   take((size_t)64 * 32 * 4);
    float*          cb    = (float*)   take((size_t)32 * 4);
    (void)ws_size; (void)n_in; (void)out_size;

    const int mb = (N + 63) / 64;                 // mm blocks
    const int gb = (N * 64 + 255) / 256;          // gather blocks (wave/node)

    // ---- build CSR (2 kernels) + compose final weights ----
    hipMemsetAsync(scnt, 0, (size_t)S * 4, stream);
    bucket_scatter_direct<<<B, 256, 0, stream>>>(ei, scnt, bedge, E, S, bcap);
    csr_fill2<<<S, 1024, 0, stream>>>(bedge, scnt, rbeg, deg, inv, adj, N, bcap);
    compose<<<1, 256, 0, stream>>>(W2b_l, W2b_r, b2b, Wlin, blin, C1, C2, cb);

    // ---- layer 1a: x[*,128] -> hA, relu ----
    mm_dual<128, 64><<<mb, 256, 0, stream>>>(x, W1a_l, W1a_r, b1a, tL, tH, u, N);
    gather_half<true, 64><<<gb, 256, 0, stream>>>(tL, adj, rbeg, deg, inv, u,      hA,      N);
    gather_half<true, 64><<<gb, 256, 0, stream>>>(tH, adj, rbeg, deg, inv, u + 32, hA + 32, N);
    // ---- layer 1b: hA -> hB, relu ----
    mm_dual<64, 64><<<mb, 256, 0, stream>>>(hA, W1b_l, W1b_r, b1b, tL, tH, u, N);
    gather_half<true, 64><<<gb, 256, 0, stream>>>(tL, adj, rbeg, deg, inv, u,      hB,      N);
    gather_half<true, 64><<<gb, 256, 0, stream>>>(tH, adj, rbeg, deg, inv, u + 32, hB + 32, N);
    // ---- layer 2a: hB -> hA, relu ----
    mm_dual<64, 64><<<mb, 256, 0, stream>>>(hB, W2a_l, W2a_r, b2a, tL, tH, u, N);
    gather_half<true, 64><<<gb, 256, 0, stream>>>(tL, adj, rbeg, deg, inv, u,      hA,      N);
    gather_half<true, 64><<<gb, 256, 0, stream>>>(tH, adj, rbeg, deg, inv, u + 32, hA + 32, N);
    // ---- layer 2b + linear composed: hA -> d_out (32-wide) ----
    mm_dual<64, 32><<<mb, 256, 0, stream>>>(hA, C1, C2, cb, tL, tH, u, N);
    gather_half<false, 32><<<gb, 256, 0, stream>>>(tL, adj, rbeg, deg, inv, u, (float*)d_out, N);
}

// Round 18
// 256.239 us; speedup vs baseline: 1.2937x; 1.2937x over previous
//
#include <hip/hip_runtime.h>
#include <hip/hip_fp16.h>

// ---------------------------------------------------------------------------
// GNNEncoder: 4x SAGEConv + linear. R17 = revert to R15 (best: 257us).
// R16's split-gather regressed (331us): NT loads on adj put HBM-miss latency
// (~900cy) on the address-dependency critical path of every t-row load, and
// doubled adj/metadata reads + launches. Reverted.
//  - compose: Wlin folded into layer 2b (C1=W2b_l@Wlin, C2=W2b_r@Wlin).
//    Final layer = mm_dual<64,32> + gather32 -> d_out directly.
//  - CSR: bucket_scatter_direct (per-(block,slice) range claims, 38K global
//    atomics total; R10 lesson: each global atomic ~32B memory-side write)
//    + csr_fill2 (LDS count/scan/cursor). Gapped adj, rbeg/deg.
//  - mm_dual K-chunk 32 (25.6KB LDS, 6 blk/CU); t,u fp16 (fp32 accumulate);
//    gather: wave/node, 8 nbr-groups x 8 dim-lanes, half8 loads.
// ---------------------------------------------------------------------------

#define CHUNK 4096          // edges per scatter block
#define EPT 16              // edges per thread (CHUNK/256)
#define SLICE_W 512         // nodes per slice (dst>>9)
#define MAXS 128            // max slices (N <= 65536)

// ---- one-pass bucket scatter: LDS rank + per-(block,slice) range claim ----
__global__ __launch_bounds__(256) void bucket_scatter_direct(
    const int* __restrict__ e32, int* __restrict__ scnt,
    unsigned* __restrict__ bedge, int E, int S, int bcap)
{
    __shared__ int h[MAXS];    // per-slice count in this block
    __shared__ int hb[MAXS];   // claimed global base
    const int tid = threadIdx.x, b = blockIdx.x;
    for (int i = tid; i < S; i += 256) h[i] = 0;
    __syncthreads();
    const int lo = b * CHUNK;
    unsigned v[EPT];
    int sl[EPT], rk[EPT];
    #pragma unroll
    for (int k = 0; k < EPT; ++k) {
        const int e = lo + k * 256 + tid;
        sl[k] = -1;
        if (e < E) {
            const int s = e32[e], d = e32[E + e];
            v[k]  = ((unsigned)s << 16) | (unsigned)d;
            sl[k] = d >> 9;
            rk[k] = atomicAdd(&h[sl[k]], 1);      // LDS rank
        }
    }
    __syncthreads();
    for (int i = tid; i < S; i += 256)
        hb[i] = h[i] ? atomicAdd(&scnt[i], h[i]) : 0;   // one claim/slice
    __syncthreads();
    #pragma unroll
    for (int k = 0; k < EPT; ++k) {
        if (sl[k] >= 0) {
            const int pos = hb[sl[k]] + rk[k];
            if (pos < bcap)    // statistical impossibility; guards OOB
                bedge[(size_t)sl[k] * bcap + pos] = v[k];
        }
    }
}

// ---- per-slice CSR finalize: rbeg, deg, inv, adj (LDS count+scan+cursor) ----
__global__ __launch_bounds__(1024) void csr_fill2(
    const unsigned* __restrict__ bedge, const int* __restrict__ scnt,
    int* __restrict__ rbeg, int* __restrict__ deg,
    float* __restrict__ inv, unsigned short* __restrict__ adj,
    int N, int bcap)
{
    __shared__ int cnt[SLICE_W];
    __shared__ int sc[SLICE_W];
    const int s = blockIdx.x, tid = threadIdx.x;
    const int n = min(scnt[s], bcap);
    const size_t base = (size_t)s * bcap;
    if (tid < SLICE_W) cnt[tid] = 0;
    __syncthreads();
    for (int i = tid; i < n; i += 1024)
        atomicAdd(&cnt[bedge[base + i] & (SLICE_W - 1)], 1);
    __syncthreads();
    if (tid < SLICE_W) sc[tid] = cnt[tid];
    __syncthreads();
    for (int off = 1; off < SLICE_W; off <<= 1) {
        int a = 0;
        if (tid < SLICE_W && tid >= off) a = sc[tid - off];
        __syncthreads();
        if (tid < SLICE_W) sc[tid] += a;
        __syncthreads();
    }
    if (tid < SLICE_W) {
        const int c = cnt[tid];
        const int excl = sc[tid] - c;
        const int node = (s << 9) + tid;
        if (node < N) {
            rbeg[node] = (int)base + excl;
            deg[node]  = c;
            inv[node]  = 1.0f / (float)(c > 0 ? c : 1);
        }
        cnt[tid] = excl;                   // becomes the cursor
    }
    __syncthreads();
    for (int i = tid; i < n; i += 1024) {
        const unsigned v = bedge[base + i];
        const int p = atomicAdd(&cnt[v & (SLICE_W - 1)], 1);   // LDS cursor
        adj[base + p] = (unsigned short)(v >> 16);
    }
}

// ---- compose: C1 = W2b_l@Wlin, C2 = W2b_r@Wlin, cb = b2b@Wlin + blin ----
__global__ __launch_bounds__(256) void compose(
    const float* __restrict__ Wl, const float* __restrict__ Wr,
    const float* __restrict__ b2, const float* __restrict__ Wlin,
    const float* __restrict__ blin, float* __restrict__ C1,
    float* __restrict__ C2, float* __restrict__ cb)
{
    __shared__ float Ws[64 * 32];
    const int tid = threadIdx.x;
    for (int i = tid * 4; i < 64 * 32; i += 1024)
        *(float4*)&Ws[i] = *(const float4*)&Wlin[i];
    __syncthreads();
    for (int idx = tid; idx < 64 * 32; idx += 256) {
        const int r = idx >> 5, c = idx & 31;
        float s1 = 0.f, s2 = 0.f;
        #pragma unroll 8
        for (int k = 0; k < 64; ++k) {
            const float w = Ws[k * 32 + c];
            s1 += Wl[r * 64 + k] * w;
            s2 += Wr[r * 64 + k] * w;
        }
        C1[idx] = s1;
        C2[idx] = s2;
    }
    if (tid < 32) {
        float s = blin[tid];
        #pragma unroll 8
        for (int k = 0; k < 64; ++k) s += b2[k] * Ws[k * 32 + tid];
        cb[tid] = s;
    }
}

// pull aggregation fused with self-term: out = (relu)(u + inv * sum_j t[adj_j])
// one wave per node: 8 neighbor-groups x 8 dim-lanes, half8 (16B) per lane.
template<bool RELU>
__global__ __launch_bounds__(256) void gather_fused(
    const __half* __restrict__ t, const unsigned short* __restrict__ adj,
    const int* __restrict__ rbeg, const int* __restrict__ deg,
    const float* __restrict__ inv, const __half* __restrict__ u,
    float* __restrict__ out, int N)
{
    const int node = (blockIdx.x * 256 + threadIdx.x) >> 6;
    const int lane = threadIdx.x & 63;
    const int grp  = lane >> 3;          // 0..7: neighbor slot in the octet
    const int d0   = (lane & 7) * 8;     // dim offset (8 dims per lane)
    if (node >= N) return;
    const int beg = rbeg[node];
    const int end = beg + deg[node];
    float a[8] = {0.f, 0.f, 0.f, 0.f, 0.f, 0.f, 0.f, 0.f};
    int j = beg + grp;
    for (; j + 8 < end; j += 16) {       // 2x unrolled: j and j+8
        const int n0 = adj[j], n1 = adj[j + 8];
        const float4 p0 = *(const float4*)(t + (size_t)n0 * 64 + d0);
        const float4 p1 = *(const float4*)(t + (size_t)n1 * 64 + d0);
        const __half2* h0 = (const __half2*)&p0;
        const __half2* h1 = (const __half2*)&p1;
        #pragma unroll
        for (int k = 0; k < 4; ++k) {
            float2 f0 = __half22float2(h0[k]);
            float2 f1 = __half22float2(h1[k]);
            a[2 * k]     += f0.x + f1.x;
            a[2 * k + 1] += f0.y + f1.y;
        }
    }
    if (j < end) {
        const float4 p0 = *(const float4*)(t + (size_t)adj[j] * 64 + d0);
        const __half2* h0 = (const __half2*)&p0;
        #pragma unroll
        for (int k = 0; k < 4; ++k) {
            float2 f0 = __half22float2(h0[k]);
            a[2 * k]     += f0.x;
            a[2 * k + 1] += f0.y;
        }
    }
    #pragma unroll
    for (int k = 0; k < 8; ++k) {
        a[k] += __shfl_xor(a[k], 8);
        a[k] += __shfl_xor(a[k], 16);
        a[k] += __shfl_xor(a[k], 32);
    }
    if (grp == 0) {
        const float vi = inv[node];
        const float4 uv = *(const float4*)(u + (size_t)node * 64 + d0);
        const __half2* uh = (const __half2*)&uv;
        float4 o0, o1;
        {
            float2 g0 = __half22float2(uh[0]);
            float2 g1 = __half22float2(uh[1]);
            float2 g2 = __half22float2(uh[2]);
            float2 g3 = __half22float2(uh[3]);
            o0.x = g0.x + a[0] * vi; o0.y = g0.y + a[1] * vi;
            o0.z = g1.x + a[2] * vi; o0.w = g1.y + a[3] * vi;
            o1.x = g2.x + a[4] * vi; o1.y = g2.y + a[5] * vi;
            o1.z = g3.x + a[6] * vi; o1.w = g3.y + a[7] * vi;
        }
        if (RELU) {
            o0.x = fmaxf(o0.x, 0.f); o0.y = fmaxf(o0.y, 0.f);
            o0.z = fmaxf(o0.z, 0.f); o0.w = fmaxf(o0.w, 0.f);
            o1.x = fmaxf(o1.x, 0.f); o1.y = fmaxf(o1.y, 0.f);
            o1.z = fmaxf(o1.z, 0.f); o1.w = fmaxf(o1.w, 0.f);
        }
        *(float4*)(out + (size_t)node * 64 + d0)     = o0;
        *(float4*)(out + (size_t)node * 64 + d0 + 4) = o1;
    }
}

// final 32-dim gather: out[node,32] = u + inv * sum_j t[adj_j]  (no relu)
// one wave per node: 16 neighbor-groups x 4 dim-lanes, half8 (16B) per lane.
__global__ __launch_bounds__(256) void gather32(
    const __half* __restrict__ t, const unsigned short* __restrict__ adj,
    const int* __restrict__ rbeg, const int* __restrict__ deg,
    const float* __restrict__ inv, const __half* __restrict__ u,
    float* __restrict__ out, int N)
{
    const int node = (blockIdx.x * 256 + threadIdx.x) >> 6;
    const int lane = threadIdx.x & 63;
    const int grp  = lane >> 2;          // 0..15: neighbor slot
    const int d0   = (lane & 3) * 8;     // dim offset (8 dims per lane)
    if (node >= N) return;
    const int beg = rbeg[node];
    const int end = beg + deg[node];
    float a[8] = {0.f, 0.f, 0.f, 0.f, 0.f, 0.f, 0.f, 0.f};
    int j = beg + grp;
    for (; j + 16 < end; j += 32) {      // 2x unrolled: j and j+16
        const int n0 = adj[j], n1 = adj[j + 16];
        const float4 p0 = *(const float4*)(t + (size_t)n0 * 32 + d0);
        const float4 p1 = *(const float4*)(t + (size_t)n1 * 32 + d0);
        const __half2* h0 = (const __half2*)&p0;
        const __half2* h1 = (const __half2*)&p1;
        #pragma unroll
        for (int k = 0; k < 4; ++k) {
            float2 f0 = __half22float2(h0[k]);
            float2 f1 = __half22float2(h1[k]);
            a[2 * k]     += f0.x + f1.x;
            a[2 * k + 1] += f0.y + f1.y;
        }
    }
    if (j < end) {
        const float4 p0 = *(const float4*)(t + (size_t)adj[j] * 32 + d0);
        const __half2* h0 = (const __half2*)&p0;
        #pragma unroll
        for (int k = 0; k < 4; ++k) {
            float2 f0 = __half22float2(h0[k]);
            a[2 * k]     += f0.x;
            a[2 * k + 1] += f0.y;
        }
    }
    // reduce across the 16 groups (lane bits 2,3,4,5)
    #pragma unroll
    for (int k = 0; k < 8; ++k) {
        a[k] += __shfl_xor(a[k], 4);
        a[k] += __shfl_xor(a[k], 8);
        a[k] += __shfl_xor(a[k], 16);
        a[k] += __shfl_xor(a[k], 32);
    }
    if (grp == 0) {
        const float vi = inv[node];
        const float4 uv = *(const float4*)(u + (size_t)node * 32 + d0);
        const __half2* uh = (const __half2*)&uv;
        float4 o0, o1;
        float2 g0 = __half22float2(uh[0]);
        float2 g1 = __half22float2(uh[1]);
        float2 g2 = __half22float2(uh[2]);
        float2 g3 = __half22float2(uh[3]);
        o0.x = g0.x + a[0] * vi; o0.y = g0.y + a[1] * vi;
        o0.z = g1.x + a[2] * vi; o0.w = g1.y + a[3] * vi;
        o1.x = g2.x + a[4] * vi; o1.y = g2.y + a[5] * vi;
        o1.z = g3.x + a[6] * vi; o1.w = g3.y + a[7] * vi;
        *(float4*)(out + (size_t)node * 32 + d0)     = o0;
        *(float4*)(out + (size_t)node * 32 + d0 + 4) = o1;
    }
}

// T[M,DOUT](fp16) = A[M,K]@Wl ; U[M,DOUT](fp16) = A[M,K]@Wr + b
// K-chunk 32. DOUT in {64,32}; CT = DOUT/16 cols per thread.
template<int K, int DOUT>
__global__ __launch_bounds__(256) void mm_dual(
    const float* __restrict__ A, const float* __restrict__ Wl,
    const float* __restrict__ Wr, const float* __restrict__ bias,
    __half* __restrict__ T, __half* __restrict__ U, int M)
{
    constexpr int CT = DOUT / 16;
    __shared__ float As[64][36];
    __shared__ float Wls[32 * DOUT];
    __shared__ float Wrs[32 * DOUT];
    const int tid  = threadIdx.x;
    const int row0 = blockIdx.x * 64;
    const int tx = tid & 15, ty = tid >> 4;
    float accT[4][CT], accU[4][CT];
    #pragma unroll
    for (int r = 0; r < 4; ++r)
        #pragma unroll
        for (int c = 0; c < CT; ++c) { accT[r][c] = 0.f; accU[r][c] = 0.f; }

    for (int kc = 0; kc < K; kc += 32) {
        if (kc) __syncthreads();
        for (int i = tid * 4; i < 64 * 32; i += 1024) {
            int r = i >> 5, c = i & 31;
            int gr = row0 + r;
            float4 v = make_float4(0.f, 0.f, 0.f, 0.f);
            if (gr < M) v = *(const float4*)&A[(size_t)gr * K + kc + c];
            *(float4*)&As[r][c] = v;
        }
        for (int i = tid * 4; i < 32 * DOUT; i += 1024) {
            *(float4*)&Wls[i] = *(const float4*)&Wl[kc * DOUT + i];
            *(float4*)&Wrs[i] = *(const float4*)&Wr[kc * DOUT + i];
        }
        __syncthreads();
        #pragma unroll 4
        for (int kk = 0; kk < 32; ++kk) {
            float a[4];
            #pragma unroll
            for (int r = 0; r < 4; ++r) a[r] = As[ty * 4 + r][kk];
            float bl[CT], br[CT];
            #pragma unroll
            for (int c = 0; c < CT; ++c) {
                bl[c] = Wls[kk * DOUT + tx * CT + c];
                br[c] = Wrs[kk * DOUT + tx * CT + c];
            }
            #pragma unroll
            for (int r = 0; r < 4; ++r)
                #pragma unroll
                for (int c = 0; c < CT; ++c) {
                    accT[r][c] += a[r] * bl[c];
                    accU[r][c] += a[r] * br[c];
                }
        }
    }

    float bv[CT];
    #pragma unroll
    for (int c = 0; c < CT; ++c) bv[c] = bias[tx * CT + c];
    #pragma unroll
    for (int r = 0; r < 4; ++r) {
        int gr = row0 + ty * 4 + r;
        if (gr >= M) continue;
        if (CT == 4) {
            union { int2 v; __half2 h[2]; } tp;
            tp.h[0] = __floats2half2_rn(accT[r][0], accT[r][1]);
            tp.h[1] = __floats2half2_rn(accT[r][2], accT[r][3]);
            *(int2*)&T[(size_t)gr * DOUT + tx * 4] = tp.v;
            union { int2 v; __half2 h[2]; } up;
            up.h[0] = __floats2half2_rn(accU[r][0] + bv[0], accU[r][1] + bv[1]);
            up.h[1] = __floats2half2_rn(accU[r][2] + bv[2], accU[r][3] + bv[3]);
            *(int2*)&U[(size_t)gr * DOUT + tx * 4] = up.v;
        } else {
            union { int v; __half2 h; } tp;
            tp.h = __floats2half2_rn(accT[r][0], accT[r][1]);
            *(int*)&T[(size_t)gr * DOUT + tx * 2] = tp.v;
            union { int v; __half2 h; } up;
            up.h = __floats2half2_rn(accU[r][0] + bv[0], accU[r][1] + bv[1]);
            *(int*)&U[(size_t)gr * DOUT + tx * 2] = up.v;
        }
    }
}

extern "C" void kernel_launch(void* const* d_in, const int* in_sizes, int n_in,
                              void* d_out, int out_size, void* d_ws, size_t ws_size,
                              hipStream_t stream) {
    const float* x     = (const float*)d_in[0];
    const int*   ei    = (const int*)  d_in[1];
    const float* W1a_l = (const float*)d_in[2];
    const float* b1a   = (const float*)d_in[3];
    const float* W1a_r = (const float*)d_in[4];
    const float* W1b_l = (const float*)d_in[5];
    const float* b1b   = (const float*)d_in[6];
    const float* W1b_r = (const float*)d_in[7];
    const float* W2a_l = (const float*)d_in[8];
    const float* b2a   = (const float*)d_in[9];
    const float* W2a_r = (const float*)d_in[10];
    const float* W2b_l = (const float*)d_in[11];
    const float* b2b   = (const float*)d_in[12];
    const float* W2b_r = (const float*)d_in[13];
    const float* Wlin  = (const float*)d_in[14];
    const float* blin  = (const float*)d_in[15];

    const int N = in_sizes[0] / 128;
    const int E = in_sizes[1] / 2;
    const int S = (N + SLICE_W - 1) / SLICE_W;       // 98 slices @ N=50k
    const int B = (E + CHUNK - 1) / CHUNK;           // 391 blocks @ E=1.6M
    const int bcap = (((E + S - 1) / S) + 2048 + 15) & ~15;  // slice capacity

    size_t o = 0;
    auto take = [&](size_t bytes) -> void* {
        void* p = (char*)d_ws + o;
        o += (bytes + 255) & ~(size_t)255;
        return p;
    };
    int*            scnt  = (int*)     take((size_t)S * 4);
    unsigned*       bedge = (unsigned*)take((size_t)S * bcap * 4);
    int*            rbeg  = (int*)     take((size_t)N * 4);
    int*            deg   = (int*)     take((size_t)N * 4);
    float*          inv   = (float*)   take((size_t)N * 4);
    unsigned short* adj   = (unsigned short*)take((size_t)S * bcap * 2);
    __half*         t     = (__half*)  take((size_t)N * 64 * 2);
    __half*         u     = (__half*)  take((size_t)N * 64 * 2);
    float*          hA    = (float*)   take((size_t)N * 64 * 4);
    float*          hB    = (float*)   take((size_t)N * 64 * 4);
    float*          C1    = (float*)   take((size_t)64 * 32 * 4);
    float*          C2    = (float*)   take((size_t)64 * 32 * 4);
    float*          cb    = (float*)   take((size_t)32 * 4);
    (void)ws_size; (void)n_in; (void)out_size;

    const int mb = (N + 63) / 64;                 // mm blocks
    const int gb = (N * 64 + 255) / 256;          // gather blocks (wave/node)

    // ---- build CSR (2 kernels) + compose final weights ----
    hipMemsetAsync(scnt, 0, (size_t)S * 4, stream);
    bucket_scatter_direct<<<B, 256, 0, stream>>>(ei, scnt, bedge, E, S, bcap);
    csr_fill2<<<S, 1024, 0, stream>>>(bedge, scnt, rbeg, deg, inv, adj, N, bcap);
    compose<<<1, 256, 0, stream>>>(W2b_l, W2b_r, b2b, Wlin, blin, C1, C2, cb);

    // ---- layer 1a: x[*,128] -> hA, relu ----
    mm_dual<128, 64><<<mb, 256, 0, stream>>>(x, W1a_l, W1a_r, b1a, t, u, N);
    gather_fused<true><<<gb, 256, 0, stream>>>(t, adj, rbeg, deg, inv, u, hA, N);
    // ---- layer 1b: hA -> hB, relu ----
    mm_dual<64, 64><<<mb, 256, 0, stream>>>(hA, W1b_l, W1b_r, b1b, t, u, N);
    gather_fused<true><<<gb, 256, 0, stream>>>(t, adj, rbeg, deg, inv, u, hB, N);
    // ---- layer 2a: hB -> hA, relu ----
    mm_dual<64, 64><<<mb, 256, 0, stream>>>(hB, W2a_l, W2a_r, b2a, t, u, N);
    gather_fused<true><<<gb, 256, 0, stream>>>(t, adj, rbeg, deg, inv, u, hA, N);
    // ---- layer 2b + linear composed: hA -> d_out (32-wide) ----
    mm_dual<64, 32><<<mb, 256, 0, stream>>>(hA, C1, C2, cb, t, u, N);
    gather32<<<gb, 256, 0, stream>>>(t, adj, rbeg, deg, inv, u, (float*)d_out, N);
}